// Round 18
// baseline (99.571 us; speedup 1.0000x reference)
//
#include <hip/hip_runtime.h>
#include <math.h>

// Adder2D: out[n,co,h,w] = -sum_{ci,kh,kw} |x[n,ci,h+kh-1,w+kw-1] - w[co,ci,kh,kw]|
// x: [16,64,32,32] f32, w: [64,64,3,3] f32, out: [16,64,32,32] f32, pad=1 stride=1.
//
// R18: max out the core:overhead instruction ratio. R17 (pipeline fully
// materialized: VGPR=32 = exact live set, SGPR=112 = both w slices, sched
// barriers held) changed NOTHING -> per-ci latency exposure eliminated as
// a theory. The only lever that ever beat 47us was R16's CG=8 (ratio
// 4.5:1 -> 9:1, -5.7%). Now CG=8 x PX=4 (R9's PX failure was confounded:
// it halved lifetime waves; here waves stay at R16's 4096 = 4/SIMD):
// thread = 4px x 8co x 8ci, per ci {6 window words + ~10 pair builds +
// one 72-float s_load} feed 432 core VALU (~27:1). Block 512 thr = 64
// out-threads x 8 cig groups (CPG=2), grid (4,8,16)=512, 2 blocks/CU.
// Proven parts kept: LW=35 conflict-free layout, readfirstlane s_load w
// (octet slices), f2 packed core, aliased LDS reduction (7x64x34 words).

#define N_   16
#define CI_  64
#define CO_  64
#define HW_  32
#define CG   8      // co per thread (= all of COB)
#define COB  8      // co per block
#define PX   4      // pixels per thread
#define RG   8      // pixel rows per block
#define CIC  16     // ci planes staged per round
#define NGRP 8      // ci groups
#define CPG  2      // ci planes per group per round
#define ROWS (RG + 2)
#define LW   35     // word0 = left halo, 1..32 = data, 33 = right halo, 34 pad
#define WSLICE 128  // floats per (co-octet,ci) w slot (72 used, 512B aligned)

#define XS_WORDS  (CIC * ROWS * LW)       // 5600 words = 22400 B
#define RED_STRIDE 34                     // words per (group,thread) slot (32 used)
#define RED_WORDS (7 * 64 * RED_STRIDE)   // 15232 words = 60928 B
#define SMEM_WORDS (RED_WORDS > XS_WORDS ? RED_WORDS : XS_WORDS)

typedef __attribute__((ext_vector_type(2))) float f2;

// ---- repack: w[co][ci][t] -> wr[(co/8)*64+ci][ (co&7)*9 + t ], 128-f slots ----
__global__ void repack_w(const float* __restrict__ w, float* __restrict__ wr)
{
    int i  = blockIdx.x * 256 + threadIdx.x;   // 4096 = (co,ci) pairs
    int co = i >> 6;
    int ci = i & 63;
    float* dst = wr + (size_t)((co >> 3) * 64 + ci) * WSLICE + (co & 7) * 9;
    const float* src = w + (size_t)co * (CI_ * 9) + ci * 9;
#pragma unroll
    for (int t = 0; t < 9; ++t) dst[t] = src[t];
}

__global__ __launch_bounds__(512, 4) void adder2d_kernel(
    const float* __restrict__ x, const float* __restrict__ wr,
    float* __restrict__ out)
{
    __shared__ __align__(16) float smem[SMEM_WORDS];
    float (*xs)[ROWS][LW] = (float (*)[ROWS][LW])smem;   // phase A
    // phase B (aliases xs after barrier): slot (g,t) at ((g*64+t)*RED_STRIDE)

    const int tid = threadIdx.x;
    const int t64 = tid & 63;            // output thread within group
    const int u   = t64 & 7;             // col-quad: output cols 4u..4u+3
    const int rl  = t64 >> 3;            // pixel row within block (0..7)
    const int cig = tid >> 6;            // ci group: 0..7 (uniform per wave)
    const int r0  = blockIdx.x * RG;
    const int co0 = blockIdx.y * COB;
    const int n   = blockIdx.z;

    const int cigs = __builtin_amdgcn_readfirstlane(cig);
    const float* wrb = wr + (size_t)blockIdx.y * 64 * WSLICE;

    // ---- zero xs once: halo words (0,33) and OOB row slots stay zero ----
    for (int i = tid; i < XS_WORDS / 4; i += 512)
        ((float4*)smem)[i] = float4{0.f, 0.f, 0.f, 0.f};

    f2 acc2[CG][2];   // [co][0]=px{0,1}, [co][1]=px{2,3}
#pragma unroll
    for (int j = 0; j < CG; ++j) { acc2[j][0] = f2{0.f, 0.f}; acc2[j][1] = f2{0.f, 0.f}; }

    const float* xn = x + (size_t)n * CI_ * HW_ * HW_;
    const int pbase = cig * CPG;

    for (int round = 0; round < CI_ / CIC; ++round) {
        const int cc0 = round * CIC;
        __syncthreads();   // protect LDS from previous round's readers
        // ---- stage CIC planes, rows r0-1..r0+8: 1280 float4 units ----
        for (int i = tid; i < CIC * ROWS * (HW_ / 4); i += 512) {
            int plane = i / (ROWS * (HW_ / 4));
            int rem   = i - plane * (ROWS * (HW_ / 4));
            int rr    = rem >> 3;
            int f4    = rem & 7;
            int gr    = r0 - 1 + rr;
            if ((unsigned)gr < HW_) {
                float4 v = ((const float4*)(xn + (size_t)(cc0 + plane) * HW_ * HW_
                                            + gr * HW_))[f4];
                float* dst = &xs[plane][rr][1 + 4 * f4];   // data words 1..32
                dst[0] = v.x; dst[1] = v.y; dst[2] = v.z; dst[3] = v.w;
            }
        }
        __syncthreads();

#pragma unroll
        for (int cil = 0; cil < CPG; ++cil) {
            const int pl  = pbase + cil;             // per-thread (LDS path)
            const int cis = cc0 + cigs * CPG + cil;  // uniform (SMEM path)

            // ---- w octet-slice (72 floats) from uniform ptr -> s_load ----
            const float* wu_p = wrb + (size_t)cis * WSLICE;
            float wu[72];
#pragma unroll
            for (int t = 0; t < 72; ++t) wu[t] = wu_p[t];

            // window: 6 words/row -> 5 overlapping pairs; lo = pairs for
            // px{0,1}, hi = pairs for px{2,3}; reused by all 8 co
            f2 lo[3][3], hi[3][3];
#pragma unroll
            for (int kh = 0; kh < 3; ++kh) {
                const float* row = &xs[pl][rl + kh][4 * u];
                float v0 = row[0], v1 = row[1], v2 = row[2];
                float v3 = row[3], v4 = row[4], v5 = row[5];
                lo[kh][0] = f2{v0, v1}; lo[kh][1] = f2{v1, v2}; lo[kh][2] = f2{v2, v3};
                hi[kh][0] = f2{v2, v3}; hi[kh][1] = f2{v3, v4}; hi[kh][2] = f2{v4, v5};
            }

            // core: 9 taps x 8 co x {2 pk_sub + 4 abs-add} = 432 VALU / ci
#pragma unroll
            for (int kh = 0; kh < 3; ++kh)
#pragma unroll
                for (int kw = 0; kw < 3; ++kw) {
#pragma unroll
                    for (int j = 0; j < CG; ++j) {
                        const float wjt = wu[j * 9 + kh * 3 + kw];
                        const f2 wv = f2{wjt, wjt};
                        acc2[j][0] += __builtin_elementwise_abs(lo[kh][kw] - wv);
                        acc2[j][1] += __builtin_elementwise_abs(hi[kh][kw] - wv);
                    }
                }
        }
    }

    // ---- combine the eight ci-group partials (red aliases dead xs) ----
    __syncthreads();   // all xs readers done before overwrite
    if (cig != 0) {
        float* rp = smem + (size_t)((cig - 1) * 64 + t64) * RED_STRIDE;
#pragma unroll
        for (int j = 0; j < CG; ++j)
            *(float4*)&rp[4 * j] =
                float4{acc2[j][0].x, acc2[j][0].y, acc2[j][1].x, acc2[j][1].y};
    }
    __syncthreads();
    if (cig == 0) {
#pragma unroll
        for (int g = 0; g < 7; ++g) {
            const float* rp = smem + (size_t)(g * 64 + t64) * RED_STRIDE;
#pragma unroll
            for (int j = 0; j < CG; ++j) {
                float4 r = *(const float4*)&rp[4 * j];
                acc2[j][0].x += r.x; acc2[j][0].y += r.y;
                acc2[j][1].x += r.z; acc2[j][1].y += r.w;
            }
        }
        float* op = out + (((size_t)n * CO_ + co0) * HW_ + (r0 + rl)) * HW_ + 4 * u;
#pragma unroll
        for (int j = 0; j < CG; ++j)
            *(float4*)&op[(size_t)j * HW_ * HW_] =
                float4{-acc2[j][0].x, -acc2[j][0].y, -acc2[j][1].x, -acc2[j][1].y};
    }
}

extern "C" void kernel_launch(void* const* d_in, const int* in_sizes, int n_in,
                              void* d_out, int out_size, void* d_ws, size_t ws_size,
                              hipStream_t stream) {
    const float* x  = (const float*)d_in[0];
    const float* wp = (const float*)d_in[1];
    float* out      = (float*)d_out;
    float* wr       = (float*)d_ws;   // 256 KiB (proven-safe footprint)

    repack_w<<<dim3(16), 256, 0, stream>>>(wp, wr);
    dim3 grid(HW_ / RG, CO_ / COB, N_);   // (4, 8, 16) = 512 blocks
    adder2d_kernel<<<grid, 512, 0, stream>>>(x, wr, out);
}